// Round 1
// baseline (362.036 us; speedup 1.0000x reference)
//
#include <hip/hip_runtime.h>

// ScaleDotProduct (BERT-style attention), B=4 H=16 S=2048 D=64, fp32 in/out.
// Strategy: bf16 MFMA flash attention.
//   prep_kernel: K -> bf16 Kb[bh][s][d]; V -> bf16 transposed Vt[bh][d][s] (in d_ws, 33.5 MB)
//   flash_kernel: per block one (bh, 64-row q-tile); online softmax over 32 key-tiles of 64.
// MFMA layouts (gfx950, verified per learn_hip m89/m91/m120):
//   A-frag: A[m=lane&15][k=quad*8+j]   B-frag: B[k=quad*8+j][n=lane&15]
//   C/D   : col=lane&15, row=quad*4+reg
// LDS tiles padded to stride 72 (144 B rows): b128 frag reads are 2-way per quarter-wave (free).

typedef __attribute__((ext_vector_type(8))) short short8;
typedef __attribute__((ext_vector_type(4))) float floatx4;

#define S_LEN 2048
#define D_DIM 64
#define NT    (S_LEN / 64)   // 32 key tiles per block
#define LDS_W 72             // padded row stride (ushorts)

static __device__ __forceinline__ unsigned short f2b(float x) {
  // fp32 -> bf16 round-to-nearest-even
  union { float f; unsigned int u; } c; c.f = x;
  unsigned int u = c.u;
  unsigned int r = (u + 0x7FFFu + ((u >> 16) & 1u)) >> 16;
  return (unsigned short)r;
}

__global__ __launch_bounds__(256) void prep_kernel(
    const float* __restrict__ kin, const float* __restrict__ vin,
    unsigned short* __restrict__ kb, unsigned short* __restrict__ vt) {
  const int tid = threadIdx.x;
  const int bx = blockIdx.x;
  if (bx < 8192) {
    // K: straight fp32 -> bf16 convert, 4 elements/thread, fully coalesced
    const int i = (bx * 256 + tid) * 4;
    const float4 f = *(const float4*)(kin + i);
    uint2 p;
    p.x = (unsigned int)f2b(f.x) | ((unsigned int)f2b(f.y) << 16);
    p.y = (unsigned int)f2b(f.z) | ((unsigned int)f2b(f.w) << 16);
    *(uint2*)(kb + i) = p;
  } else {
    // V transpose: coalesced reads (lanes span d), 32B scattered writes (acceptable)
    const int b2 = bx - 8192;           // 0..2047
    const int bh = b2 >> 5;
    const int kc = b2 & 31;
    const int d = tid & 63;
    const int kgl = tid >> 6;           // 0..3
    const int k0 = kc * 64 + kgl * 16;  // 16 keys per thread
    const float* vp = vin + ((bh * S_LEN + k0) * D_DIM) + d;
    unsigned int p[8];
#pragma unroll
    for (int jj = 0; jj < 8; ++jj) {
      unsigned short lo = f2b(vp[(2 * jj) * D_DIM]);
      unsigned short hi = f2b(vp[(2 * jj + 1) * D_DIM]);
      p[jj] = (unsigned int)lo | ((unsigned int)hi << 16);
    }
    unsigned short* dst = vt + (bh * D_DIM + d) * S_LEN + k0;
    uint4 w0; w0.x = p[0]; w0.y = p[1]; w0.z = p[2]; w0.w = p[3];
    uint4 w1; w1.x = p[4]; w1.y = p[5]; w1.z = p[6]; w1.w = p[7];
    *(uint4*)(dst) = w0;
    *(uint4*)(dst + 8) = w1;
  }
}

__global__ __launch_bounds__(256) void flash_kernel(
    const float* __restrict__ qin, const unsigned short* __restrict__ kb,
    const unsigned short* __restrict__ vt, const float* __restrict__ mask,
    float* __restrict__ out) {
  __shared__ unsigned short Qs[64 * LDS_W];
  __shared__ unsigned short Ks[64 * LDS_W];
  __shared__ unsigned short Vs[64 * LDS_W];
  __shared__ unsigned short Ps[4 * 16 * LDS_W];  // per-wave P staging

  const int tid = threadIdx.x;
  const int w = tid >> 6;        // wave id 0..3 -> q rows w*16..w*16+15
  const int lane = tid & 63;
  const int quad = lane >> 4;
  const int lm = lane & 15;
  const int bx = blockIdx.x;     // q tile 0..31
  const int bh = blockIdx.y;     // 0..63
  const int b = bh >> 4;         // batch (H=16)
  const int q0 = bx * 64;

  // ---- stage Q tile (scale 1/8 folded in, exact) ----
  {
    const int row = tid >> 2;
    const int c0 = (tid & 3) * 16;
    const float* qp = qin + ((bh * S_LEN + q0 + row) * D_DIM) + c0;
    unsigned int p[8];
#pragma unroll
    for (int jj = 0; jj < 8; ++jj) {
      unsigned short lo = f2b(qp[2 * jj] * 0.125f);
      unsigned short hi = f2b(qp[2 * jj + 1] * 0.125f);
      p[jj] = (unsigned int)lo | ((unsigned int)hi << 16);
    }
    uint4 w0; w0.x = p[0]; w0.y = p[1]; w0.z = p[2]; w0.w = p[3];
    uint4 w1; w1.x = p[4]; w1.y = p[5]; w1.z = p[6]; w1.w = p[7];
    *(uint4*)&Qs[row * LDS_W + c0] = w0;
    *(uint4*)&Qs[row * LDS_W + c0 + 8] = w1;
  }
  __syncthreads();

  const short8 aq0 = *(const short8*)&Qs[(w * 16 + lm) * LDS_W + quad * 8];
  const short8 aq1 = *(const short8*)&Qs[(w * 16 + lm) * LDS_W + 32 + quad * 8];

  float m_run[4], l_run[4];
  floatx4 o[4];
#pragma unroll
  for (int r = 0; r < 4; ++r) { m_run[r] = -3.0e38f; l_run[r] = 0.f; }
#pragma unroll
  for (int dt = 0; dt < 4; ++dt) o[dt] = (floatx4){0.f, 0.f, 0.f, 0.f};

  const unsigned short* kbase = kb + bh * (S_LEN * D_DIM);
  const unsigned short* vbase = vt + bh * (D_DIM * S_LEN);
  const float* mbase = mask + b * S_LEN;
  unsigned short* pw = &Ps[w * 16 * LDS_W];

  for (int t = 0; t < NT; ++t) {
    const int k0 = t * 64;
    __syncthreads();  // previous tile's LDS reads done before overwrite
    // ---- stage K (64 keys x 64 d) and V^T (64 d x 64 keys), bf16, 16B chunks ----
#pragma unroll
    for (int c = 0; c < 2; ++c) {
      const int cc = c * 256 + tid;     // 0..511 chunks of 8 ushorts
      const int row = cc >> 3;
      const int col = (cc & 7) * 8;
      uint4 kv = *(const uint4*)(kbase + (k0 + row) * D_DIM + col);
      *(uint4*)&Ks[row * LDS_W + col] = kv;
      uint4 vv = *(const uint4*)(vbase + row * S_LEN + k0 + col);
      *(uint4*)&Vs[row * LDS_W + col] = vv;
    }
    __syncthreads();

    // ---- S strip = Q(16 rows) K^T (64 keys), scale already folded ----
    floatx4 s[4];
#pragma unroll
    for (int kt = 0; kt < 4; ++kt) {
      const short8 bk0 = *(const short8*)&Ks[(kt * 16 + lm) * LDS_W + quad * 8];
      const short8 bk1 = *(const short8*)&Ks[(kt * 16 + lm) * LDS_W + 32 + quad * 8];
      floatx4 acc = (floatx4){0.f, 0.f, 0.f, 0.f};
      acc = __builtin_amdgcn_mfma_f32_16x16x32_bf16(aq0, bk0, acc, 0, 0, 0);
      acc = __builtin_amdgcn_mfma_f32_16x16x32_bf16(aq1, bk1, acc, 0, 0, 0);
      const float mval = mbase[k0 + kt * 16 + lm];  // additive mask, per key col
#pragma unroll
      for (int r = 0; r < 4; ++r) acc[r] += mval;
      s[kt] = acc;
    }

    // ---- online softmax (row stats across 16 lanes of the quad) ----
    float alpha[4];
#pragma unroll
    for (int r = 0; r < 4; ++r) {
      float mx = fmaxf(fmaxf(s[0][r], s[1][r]), fmaxf(s[2][r], s[3][r]));
#pragma unroll
      for (int off = 8; off >= 1; off >>= 1)
        mx = fmaxf(mx, __shfl_xor(mx, off, 64));
      const float mn = fmaxf(m_run[r], mx);
      alpha[r] = __expf(m_run[r] - mn);
      m_run[r] = mn;
      float sum = 0.f;
#pragma unroll
      for (int kt = 0; kt < 4; ++kt) {
        const float p = __expf(s[kt][r] - mn);
        s[kt][r] = p;
        sum += p;
      }
#pragma unroll
      for (int off = 8; off >= 1; off >>= 1)
        sum += __shfl_xor(sum, off, 64);
      l_run[r] = l_run[r] * alpha[r] + sum;
    }
#pragma unroll
    for (int dt = 0; dt < 4; ++dt) {
#pragma unroll
      for (int r = 0; r < 4; ++r) o[dt][r] *= alpha[r];
    }

    // ---- P: C-layout -> bf16 -> per-wave LDS -> A-layout (m120 round-trip) ----
#pragma unroll
    for (int kt = 0; kt < 4; ++kt) {
#pragma unroll
      for (int r = 0; r < 4; ++r)
        pw[(quad * 4 + r) * LDS_W + kt * 16 + lm] = f2b(s[kt][r]);
    }
    __threadfence_block();  // order LDS write->read (wave-internal, no barrier needed)
    const short8 ap0 = *(const short8*)&pw[lm * LDS_W + quad * 8];
    const short8 ap1 = *(const short8*)&pw[lm * LDS_W + 32 + quad * 8];

    // ---- O strip += P V  (B-operand from transposed V: key-contiguous) ----
#pragma unroll
    for (int dt = 0; dt < 4; ++dt) {
      const short8 bv0 = *(const short8*)&Vs[(dt * 16 + lm) * LDS_W + quad * 8];
      const short8 bv1 = *(const short8*)&Vs[(dt * 16 + lm) * LDS_W + 32 + quad * 8];
      o[dt] = __builtin_amdgcn_mfma_f32_16x16x32_bf16(ap0, bv0, o[dt], 0, 0, 0);
      o[dt] = __builtin_amdgcn_mfma_f32_16x16x32_bf16(ap1, bv1, o[dt], 0, 0, 0);
    }
  }

  // ---- epilogue: divide by l, store fp32 (lane-contiguous in d => coalesced 64B) ----
#pragma unroll
  for (int r = 0; r < 4; ++r) {
    const float inv = 1.0f / l_run[r];
    const int row = q0 + w * 16 + quad * 4 + r;
    float* op = out + (bh * S_LEN + row) * D_DIM + lm;
#pragma unroll
    for (int dt = 0; dt < 4; ++dt) op[dt * 16] = o[dt][r] * inv;
  }
}

extern "C" void kernel_launch(void* const* d_in, const int* in_sizes, int n_in,
                              void* d_out, int out_size, void* d_ws, size_t ws_size,
                              hipStream_t stream) {
  const float* q = (const float*)d_in[0];
  const float* k = (const float*)d_in[1];
  const float* v = (const float*)d_in[2];
  const float* mask = (const float*)d_in[3];
  // d_in[4] = attention_head_size (64), compile-time constant here
  float* out = (float*)d_out;

  // workspace: Kb (16.78 MB bf16) + Vt (16.78 MB bf16) = 33.55 MB
  unsigned short* kb = (unsigned short*)d_ws;
  unsigned short* vt = kb + (size_t)64 * S_LEN * D_DIM;

  prep_kernel<<<8192 + 2048, 256, 0, stream>>>(k, v, kb, vt);
  flash_kernel<<<dim3(32, 64), 256, 0, stream>>>(q, kb, vt, mask, out);
}

// Round 3
// 332.380 us; speedup vs baseline: 1.0892x; 1.0892x over previous
//
#include <hip/hip_runtime.h>

// ScaleDotProduct (BERT attention) B=4 H=16 S=2048 D=64 fp32 in/out.
// bf16 MFMA flash attention, key-split waves, fixed-max softmax (m=12),
// S^T = K*Q^T so P^T (C-layout) is directly the PV B-fragment (no transpose).
// K/V staged via global_load_lds(16B) with XOR-swizzled global addressing.
// MFMA 16x16x32 layouts (verified m89/m91): A[m=lane&15][k=quad*8+j],
// B[k=quad*8+j][n=lane&15], C/D: col=lane&15, row=quad*4+reg.

typedef __attribute__((ext_vector_type(8))) short short8;
typedef __attribute__((ext_vector_type(4))) float floatx4;

#define S_LEN 2048
#define D_DIM 64
#define NT    32
#define L2E   1.44269504089f

static __device__ __forceinline__ unsigned short f2b(float x) {  // RNE
  union { float f; unsigned int u; } c; c.f = x;
  return (unsigned short)((c.u + 0x7FFFu + ((c.u >> 16) & 1u)) >> 16);
}
static __device__ __forceinline__ unsigned int rhu(float x) {    // round-half-up bf16 bits
  union { float f; unsigned int u; } c; c.f = x;
  return (c.u + 0x8000u) >> 16;
}
static __device__ __forceinline__ void load_lds16(const void* g, void* l) {
  __builtin_amdgcn_global_load_lds(
      (const __attribute__((address_space(1))) unsigned int*)g,
      (__attribute__((address_space(3))) unsigned int*)l, 16, 0, 0);
}

__global__ __launch_bounds__(256) void prep_kernel(
    const float* __restrict__ kin, const float* __restrict__ vin,
    unsigned short* __restrict__ kb, unsigned short* __restrict__ vt) {
  const int tid = threadIdx.x, bx = blockIdx.x;
  if (bx < 8192) {
    // K: fp32 -> bf16, coalesced
    const int i = (bx * 256 + tid) * 4;
    const float4 f = *(const float4*)(kin + i);
    uint2 p;
    p.x = (unsigned)f2b(f.x) | ((unsigned)f2b(f.y) << 16);
    p.y = (unsigned)f2b(f.z) | ((unsigned)f2b(f.w) << 16);
    *(uint2*)(kb + i) = p;
  } else {
    // V transpose via LDS: coalesced reads, 128B-contiguous writes
    __shared__ unsigned short Lt[64 * 72];
    const int b2 = bx - 8192, bh = b2 >> 5, k0 = (b2 & 31) * 64;
    const int r = tid >> 2, c0 = (tid & 3) * 16;
    const float* vp = vin + ((size_t)(bh * S_LEN + k0 + r)) * D_DIM + c0;
    unsigned int pk[8];
#pragma unroll
    for (int h = 0; h < 2; ++h) {
      float4 a = *(const float4*)(vp + h * 8);
      float4 b = *(const float4*)(vp + h * 8 + 4);
      pk[h * 4 + 0] = (unsigned)f2b(a.x) | ((unsigned)f2b(a.y) << 16);
      pk[h * 4 + 1] = (unsigned)f2b(a.z) | ((unsigned)f2b(a.w) << 16);
      pk[h * 4 + 2] = (unsigned)f2b(b.x) | ((unsigned)f2b(b.y) << 16);
      pk[h * 4 + 3] = (unsigned)f2b(b.z) | ((unsigned)f2b(b.w) << 16);
    }
    *(uint4*)&Lt[r * 72 + c0] = make_uint4(pk[0], pk[1], pk[2], pk[3]);
    *(uint4*)&Lt[r * 72 + c0 + 8] = make_uint4(pk[4], pk[5], pk[6], pk[7]);
    __syncthreads();
#pragma unroll
    for (int it = 0; it < 2; ++it) {
      const int ci = it * 256 + tid, d = ci >> 3, kc8 = ci & 7;
      unsigned short vals[8];
#pragma unroll
      for (int j = 0; j < 8; ++j) {  // rotated order -> conflict-free columns
        const int jj = (j + kc8) & 7;
        vals[jj] = Lt[(kc8 * 8 + jj) * 72 + d];
      }
      uint4 o;
      o.x = (unsigned)vals[0] | ((unsigned)vals[1] << 16);
      o.y = (unsigned)vals[2] | ((unsigned)vals[3] << 16);
      o.z = (unsigned)vals[4] | ((unsigned)vals[5] << 16);
      o.w = (unsigned)vals[6] | ((unsigned)vals[7] << 16);
      *(uint4*)(vt + ((size_t)(bh * D_DIM + d)) * S_LEN + k0 + kc8 * 8) = o;
    }
  }
}

union SMem {
  struct {
    unsigned short Ks[64 * 64];  // swizzled: slot c holds chunk c^(row&7)
    unsigned short Vs[64 * 64];  // rows = d, cols = key (swizzled)
    unsigned short Qs[64 * 64];  // rows = q (swizzled)
  } m;
  float Os[64][68];              // epilogue accumulator [q][d], padded
};

__global__ __launch_bounds__(256, 4) void flash_kernel(
    const float* __restrict__ qin, const unsigned short* __restrict__ kb,
    const unsigned short* __restrict__ vt, const float* __restrict__ mask,
    float* __restrict__ out) {
  __shared__ SMem sm;
  __shared__ float Msc[64];
  __shared__ float Ls[4][64];

  const int tid = threadIdx.x;
  const int w = tid >> 6, lane = tid & 63, quad = lane >> 4, lm = lane & 15;
  const int bx = blockIdx.x, bh = blockIdx.y, b = bh >> 4;
  const int q0 = bx * 64;
  const int l7 = lm & 7;

  // ---- stage Q (bf16, *0.125, swizzled) ----
  {
    const int row = tid >> 2, r7 = row & 7;
    const float* qp = qin + ((size_t)(bh * S_LEN + q0 + row)) * D_DIM + (tid & 3) * 16;
#pragma unroll
    for (int h = 0; h < 2; ++h) {
      const int chunk = (tid & 3) * 2 + h;
      float4 a = *(const float4*)(qp + h * 8);
      float4 c = *(const float4*)(qp + h * 8 + 4);
      uint4 o;
      o.x = (unsigned)f2b(a.x * 0.125f) | ((unsigned)f2b(a.y * 0.125f) << 16);
      o.y = (unsigned)f2b(a.z * 0.125f) | ((unsigned)f2b(a.w * 0.125f) << 16);
      o.z = (unsigned)f2b(c.x * 0.125f) | ((unsigned)f2b(c.y * 0.125f) << 16);
      o.w = (unsigned)f2b(c.z * 0.125f) | ((unsigned)f2b(c.w * 0.125f) << 16);
      *(uint4*)&sm.m.Qs[row * 64 + ((chunk ^ r7) * 8)] = o;
    }
  }

  // ---- per-lane staging sources (swizzled on the global side) ----
  const int rl = lane >> 3, cl = lane & 7;
  const int swz = (cl ^ rl) * 8;
  const unsigned short* kp0 = kb + (size_t)bh * S_LEN * D_DIM + (w * 16 + rl) * 64 + swz;
  const unsigned short* kp1 = kp0 + 8 * 64;
  const unsigned short* vp0 = vt + (size_t)bh * D_DIM * S_LEN + (w * 16 + rl) * S_LEN + swz;
  const unsigned short* vp1 = vp0 + 8 * S_LEN;
  unsigned short* ldsK0 = &sm.m.Ks[(w * 16) * 64];
  unsigned short* ldsK1 = &sm.m.Ks[(w * 16 + 8) * 64];
  unsigned short* ldsV0 = &sm.m.Vs[(w * 16) * 64];
  unsigned short* ldsV1 = &sm.m.Vs[(w * 16 + 8) * 64];

  // precomputed fragment indices
  const int kidx0 = (w * 16 + lm) * 64 + ((quad ^ l7) * 8);
  const int kidx1 = (w * 16 + lm) * 64 + (((4 + quad) ^ l7) * 8);
  const int vc0 = (((2 * w + (quad >> 1)) & 7) ^ l7) * 8 + 4 * (quad & 1);
  const int vc1 = (((2 * w + ((quad + 1) >> 1)) & 7) ^ l7) * 8 + 4 * ((quad + 1) & 1);
  const float* mrow = mask + b * S_LEN;

  floatx4 o[4][4];  // [dt][qs]
#pragma unroll
  for (int dt = 0; dt < 4; ++dt)
#pragma unroll
    for (int qs = 0; qs < 4; ++qs) o[dt][qs] = (floatx4){0.f, 0.f, 0.f, 0.f};
  float lsum[4] = {0.f, 0.f, 0.f, 0.f};

  for (int t = 0; t < NT; ++t) {
    __syncthreads();  // prev-iter LDS readers done
    load_lds16(kp0 + t * 4096, ldsK0);
    load_lds16(kp1 + t * 4096, ldsK1);
    load_lds16(vp0 + t * 64, ldsV0);
    load_lds16(vp1 + t * 64, ldsV1);
    if (tid < 64) {
      const float mv = mrow[t * 64 + tid];
      Msc[tid] = fmaf(mv, L2E, -12.0f * L2E);  // (mask-12)*log2e
    }
    __syncthreads();  // staging (vmcnt drained by barrier) complete

    const short8 ak0 = *(const short8*)&sm.m.Ks[kidx0];
    const short8 ak1 = *(const short8*)&sm.m.Ks[kidx1];
    const floatx4 mc = *(const floatx4*)&Msc[w * 16 + quad * 4];

    // S^T strips + softmax + pack P^T B-frags
    short8 bp[4];
#pragma unroll
    for (int qs = 0; qs < 4; ++qs) {
      const short8 bq0 = *(const short8*)&sm.m.Qs[(qs * 16 + lm) * 64 + ((quad ^ l7) * 8)];
      const short8 bq1 = *(const short8*)&sm.m.Qs[(qs * 16 + lm) * 64 + (((4 + quad) ^ l7) * 8)];
      floatx4 st = (floatx4){0.f, 0.f, 0.f, 0.f};
      st = __builtin_amdgcn_mfma_f32_16x16x32_bf16(ak0, bq0, st, 0, 0, 0);
      st = __builtin_amdgcn_mfma_f32_16x16x32_bf16(ak1, bq1, st, 0, 0, 0);
      float p[4];
#pragma unroll
      for (int r = 0; r < 4; ++r) {
        p[r] = __builtin_amdgcn_exp2f(fmaf(st[r], L2E, mc[r]));
        lsum[qs] += p[r];
      }
      union { unsigned int u[4]; short8 s; } pb;
      pb.u[0] = rhu(p[0]) | (rhu(p[1]) << 16);
      pb.u[1] = rhu(p[2]) | (rhu(p[3]) << 16);
      pb.u[2] = 0; pb.u[3] = 0;
      bp[qs] = pb.s;
    }

    // O^T += V^T * P^T  (A j=0..7 = keys quad*4..+7; B zero at j>=4)
#pragma unroll
    for (int dt = 0; dt < 4; ++dt) {
      const int vrow = (dt * 16 + lm) * 64;
      union { uint2 u2[2]; short8 s; } av;
      av.u2[0] = *(const uint2*)&sm.m.Vs[vrow + vc0];
      av.u2[1] = *(const uint2*)&sm.m.Vs[vrow + vc1];
#pragma unroll
      for (int qs = 0; qs < 4; ++qs)
        o[dt][qs] = __builtin_amdgcn_mfma_f32_16x16x32_bf16(av.s, bp[qs], o[dt][qs], 0, 0, 0);
    }
  }

  // ---- l: reduce over quads (keys), publish per-wave partials ----
#pragma unroll
  for (int qs = 0; qs < 4; ++qs) {
    float v = lsum[qs];
    v += __shfl_xor(v, 16, 64);
    v += __shfl_xor(v, 32, 64);
    lsum[qs] = v;
  }
  if (quad == 0) {
#pragma unroll
    for (int qs = 0; qs < 4; ++qs) Ls[w][qs * 16 + lm] = lsum[qs];
  }

  // ---- O^T cross-wave reduction through Os[q][d] (aliases Ks/Vs/Qs) ----
#pragma unroll
  for (int ph = 0; ph < 4; ++ph) {
    __syncthreads();
    if (w == ph) {
#pragma unroll
      for (int dt = 0; dt < 4; ++dt)
#pragma unroll
        for (int qs = 0; qs < 4; ++qs) {
          float* dst = &sm.Os[qs * 16 + lm][dt * 16 + quad * 4];
          if (ph == 0) {
            *(floatx4*)dst = o[dt][qs];
          } else {
            floatx4 cur = *(const floatx4*)dst;
            *(floatx4*)dst = cur + o[dt][qs];
          }
        }
    }
  }
  __syncthreads();

  // ---- epilogue: /l, coalesced fp32 store ----
  {
    const int q = tid >> 2, dc = (tid & 3) * 16;
    const float l = Ls[0][q] + Ls[1][q] + Ls[2][q] + Ls[3][q];
    const float inv = 1.0f / l;
    float* outp = out + ((size_t)(bh * S_LEN + q0 + q)) * D_DIM + dc;
#pragma unroll
    for (int i = 0; i < 4; ++i) {
      floatx4 v = *(const floatx4*)&sm.Os[q][dc + i * 4];
      v *= inv;
      *(floatx4*)(outp + i * 4) = v;
    }
  }
}

extern "C" void kernel_launch(void* const* d_in, const int* in_sizes, int n_in,
                              void* d_out, int out_size, void* d_ws, size_t ws_size,
                              hipStream_t stream) {
  const float* q = (const float*)d_in[0];
  const float* k = (const float*)d_in[1];
  const float* v = (const float*)d_in[2];
  const float* mask = (const float*)d_in[3];
  float* out = (float*)d_out;

  unsigned short* kb = (unsigned short*)d_ws;                       // 16.78 MB
  unsigned short* vt = kb + (size_t)64 * S_LEN * D_DIM;             // 16.78 MB

  prep_kernel<<<8192 + 2048, 256, 0, stream>>>(k, v, kb, vt);
  flash_kernel<<<dim3(32, 64), 256, 0, stream>>>(q, kb, vt, mask, out);
}